// Round 1
// baseline (97066.693 us; speedup 1.0000x reference)
//
#include <hip/hip_runtime.h>
#include <math.h>

// Problem constants
#define B_   64
#define U_   1024
#define E_   512
#define D_   640
#define L4_  2560
#define TC   64          // time-chunk length
#define NCH  16          // number of chunks (TC*NCH == U_)
#define NBLK 320         // blocks in the persistent sequence kernel (2 d's each)

// ---------------------------------------------------------------------------
// GEMM: C[t][n][b] = bias[n] + sum_k A[m][k] * W[k][n],  m = t*64 + b
// MODE 0: A row m comes from embed[targets[b][t0+t]] (gather), K = 512
// MODE 1: A is h0c with layout [t][k][b] (stride 640*64 per t),  K = 640
// Block tile 128x128, 256 threads, 8x8 per-thread tile, BK=8.  (unchanged)
// ---------------------------------------------------------------------------
template <int MODE>
__global__ __launch_bounds__(256) void gemm_kernel(
    const float* __restrict__ A,        // MODE0: embed [V][E]; MODE1: h0c [TC][640][64]
    const int*   __restrict__ targets,  // [B][U], used in MODE0
    const float* __restrict__ Wm,       // [K][2560]
    const float* __restrict__ bias,     // [2560]
    float* __restrict__ xz,             // [TC][2560][64]
    int K, int t0)
{
    const int tid = threadIdx.x;
    const int m0 = blockIdx.x * 128;
    const int n0 = blockIdx.y * 128;

    __shared__ float As[8][132];
    __shared__ float Bs[8][132];

    float acc[8][8];
#pragma unroll
    for (int i = 0; i < 8; ++i)
#pragma unroll
        for (int j = 0; j < 8; ++j) acc[i][j] = 0.f;

    const float* a_ptr;
    int a_ml = 0, a_kq = 0, a_k = 0;
    if (MODE == 0) {
        a_ml = tid & 127;
        a_kq = (tid >> 7) * 4;
        int m  = m0 + a_ml;
        int b  = m & 63;
        int tl = m >> 6;
        int idx = targets[b * U_ + t0 + tl];
        a_ptr = A + (size_t)idx * E_ + a_kq;
    } else {
        a_k  = tid >> 5;
        a_ml = (tid & 31) * 4;
        int m  = m0 + a_ml;
        int b  = m & 63;
        int tl = m >> 6;
        a_ptr = A + (size_t)tl * (D_ * 64) + (size_t)a_k * 64 + b;
    }
    const int b_k  = tid >> 5;
    const int b_n4 = (tid & 31) * 4;

    const int tx = tid & 15;
    const int ty = tid >> 4;

    for (int k0 = 0; k0 < K; k0 += 8) {
        if (MODE == 0) {
            float4 av = *(const float4*)(a_ptr + k0);
            As[a_kq + 0][a_ml] = av.x;
            As[a_kq + 1][a_ml] = av.y;
            As[a_kq + 2][a_ml] = av.z;
            As[a_kq + 3][a_ml] = av.w;
        } else {
            float4 av = *(const float4*)(a_ptr + (size_t)k0 * 64);
            *(float4*)&As[a_k][a_ml] = av;
        }
        {
            float4 bv = *(const float4*)(Wm + (size_t)(k0 + b_k) * L4_ + n0 + b_n4);
            *(float4*)&Bs[b_k][b_n4] = bv;
        }
        __syncthreads();

#pragma unroll
        for (int k = 0; k < 8; ++k) {
            float af[8], bf[8];
            *(float4*)&af[0] = *(const float4*)&As[k][ty * 8];
            *(float4*)&af[4] = *(const float4*)&As[k][ty * 8 + 4];
            *(float4*)&bf[0] = *(const float4*)&Bs[k][tx * 8];
            *(float4*)&bf[4] = *(const float4*)&Bs[k][tx * 8 + 4];
#pragma unroll
            for (int i = 0; i < 8; ++i)
#pragma unroll
                for (int j = 0; j < 8; ++j) acc[i][j] += af[i] * bf[j];
        }
        __syncthreads();
    }

#pragma unroll
    for (int i = 0; i < 8; ++i) {
        int m  = m0 + ty * 8 + i;
        int tl = m >> 6;
        int b  = m & 63;
        float* outp = xz + (size_t)tl * (L4_ * 64) + b;
#pragma unroll
        for (int j = 0; j < 8; ++j) {
            int n = n0 + tx * 8 + j;
            outp[(size_t)n * 64] = acc[i][j] + bias[n];
        }
    }
}

// ---------------------------------------------------------------------------
// Pre-transpose recurrent weights:  Up[d][k][g] = Uw[k][g*640 + d]
// so the sequence kernel reads one contiguous float4 (all 4 gates of one d)
// per k via wave-uniform scalar loads. Run once per call, both layers.
// ---------------------------------------------------------------------------
__global__ __launch_bounds__(256) void prep_up_kernel(
    const float* __restrict__ U0w, const float* __restrict__ U1w,
    float* __restrict__ Up0, float* __restrict__ Up1)
{
    const int k = blockIdx.x;                       // 0..639
    const float* Uw = blockIdx.y ? U1w : U0w;
    float*       Up = blockIdx.y ? Up1 : Up0;
    for (int d = threadIdx.x; d < D_; d += 256) {   // coalesced reads over d
        float4 v;
        v.x = Uw[(size_t)k * L4_ + d];
        v.y = Uw[(size_t)k * L4_ + 640  + d];
        v.z = Uw[(size_t)k * L4_ + 1280 + d];
        v.w = Uw[(size_t)k * L4_ + 1920 + d];
        *(float4*)(Up + (size_t)d * 2560 + (size_t)k * 4) = v;
    }
}

// ---------------------------------------------------------------------------
// Device-scope grid barrier (generation counting, self-resetting).
//  - arrival: RELEASE fetch_add -> s_waitcnt + buffer_wbl2 sc1 publishes this
//    block's h stores across non-coherent per-XCD L2s before the count lands.
//  - spin: RELAXED agent loads (sc1, sees remote update, no inv per poll).
//  - exit: one acquire fence -> single buffer_inv so next step's h loads
//    refill fresh lines; everything else (Up/xz) refills from LLC cheaply.
// Safety: NBLK=320 blocks, __launch_bounds__(256,2) guarantees >=2 blocks/CU
// (512 slots >= 320), so all blocks are co-resident; no deadlock.
// ---------------------------------------------------------------------------
__device__ __forceinline__ void grid_barrier(unsigned* cnt, unsigned* gen)
{
    __syncthreads();                    // all block stores complete (vmcnt) here
    if (threadIdx.x == 0) {
        unsigned g = __hip_atomic_load(gen, __ATOMIC_RELAXED, __HIP_MEMORY_SCOPE_AGENT);
        unsigned a = __hip_atomic_fetch_add(cnt, 1u, __ATOMIC_RELEASE, __HIP_MEMORY_SCOPE_AGENT);
        if (a == (unsigned)(NBLK - 1)) {
            __hip_atomic_store(cnt, 0u, __ATOMIC_RELAXED, __HIP_MEMORY_SCOPE_AGENT);
            __hip_atomic_store(gen, g + 1u, __ATOMIC_RELEASE, __HIP_MEMORY_SCOPE_AGENT);
        } else {
            while (__hip_atomic_load(gen, __ATOMIC_RELAXED, __HIP_MEMORY_SCOPE_AGENT) == g)
                __builtin_amdgcn_s_sleep(2);
        }
        __builtin_amdgcn_fence(__ATOMIC_ACQUIRE, "agent");
    }
    __syncthreads();
}

// ---------------------------------------------------------------------------
// Persistent LSTM sequence kernel: runs TC=64 timesteps in ONE launch.
// Grid: 320 blocks x 256 threads; block owns hidden dims d0, d0+1.
// Thread (b, ks): b = tid&63 (batch lane, coalesced h loads), ks = tid>>6
// (k-split, 160 k per thread). Recurrent weights via wave-uniform s_load of
// pre-transposed Up (contiguous float4 per k per d). c-state lives in
// registers for the whole chunk. xz + masked-h prefetched at step start so
// the epilogue hides under the k-loop. 63 grid barriers per launch.
// ---------------------------------------------------------------------------
__global__ __launch_bounds__(256, 2) void lstm_seq_kernel(
    const float* __restrict__ xz,      // [TC][2560][64]
    const float* __restrict__ Up,      // [640][640][4] pre-transposed
    float* __restrict__ hA,            // [640][64] ping
    float* __restrict__ hB,            // [640][64] pong
    float* __restrict__ c_st,          // [640][64]
    const int* __restrict__ lens,      // [64]
    float* __restrict__ hc_out,        // [TC][640][64]
    int t0,
    unsigned* __restrict__ bar)        // bar[0]=cnt, bar[1]=gen
{
    const int d0 = blockIdx.x * 2;
    const int b  = threadIdx.x & 63;
    const int ks = threadIdx.x >> 6;            // 0..3
    const int kbeg = ks * 160;

    __shared__ float red[32][64];               // [(dd*4+g)*4 + ks][b]

    const float* up0 = Up + (size_t)d0 * 2560;  // d0   : [k][4] contiguous
    const float* up1 = up0 + 2560;              // d0+1

    // epilogue-private state (threads 0..127: dd = tid>>6 in {0,1}, bb = tid&63)
    const bool epi = threadIdx.x < 128;
    int   ed = 0, eb = 0, len_b = 0;
    float c_reg = 0.f;
    if (epi) {
        ed    = d0 + (threadIdx.x >> 6);
        eb    = threadIdx.x & 63;
        c_reg = c_st[ed * 64 + eb];             // c never crosses blocks
        len_b = lens[eb];
    }

    for (int tl = 0; tl < TC; ++tl) {
        const int t = t0 + tl;
        const float* hp = (t & 1) ? hB : hA;    // same parity rule as before
        float*       hn = (t & 1) ? hA : hB;

        // prefetch epilogue operands early -> latency hidden under k-loop
        float xzv[4], hp_epi = 0.f;
        if (epi) {
            const float* xzp = xz + (size_t)tl * (L4_ * 64) + eb;
#pragma unroll
            for (int g = 0; g < 4; ++g)
                xzv[g] = xzp[(size_t)(ed + 640 * g) * 64];
            hp_epi = hp[ed * 64 + eb];
        }

        float p[8];
#pragma unroll
        for (int i = 0; i < 8; ++i) p[i] = 0.f;

        const float* hpb = hp + b;
        // 16-deep load groups: ~16 outstanding h loads/wave keeps even a
        // 1-wave/SIMD CU FMA-bound (2560 FMA cyc > 10x200 cyc load latency)
        for (int kk = kbeg; kk < kbeg + 160; kk += 16) {
            float hv[16];
#pragma unroll
            for (int j = 0; j < 16; ++j) hv[j] = hpb[(kk + j) << 6];
#pragma unroll
            for (int j = 0; j < 16; ++j) {
                const float4 ua = *(const float4*)(up0 + ((kk + j) << 2));
                const float4 ub = *(const float4*)(up1 + ((kk + j) << 2));
                p[0] += hv[j] * ua.x; p[1] += hv[j] * ua.y;
                p[2] += hv[j] * ua.z; p[3] += hv[j] * ua.w;
                p[4] += hv[j] * ub.x; p[5] += hv[j] * ub.y;
                p[6] += hv[j] * ub.z; p[7] += hv[j] * ub.w;
            }
        }
#pragma unroll
        for (int i = 0; i < 8; ++i) red[i * 4 + ks][b] = p[i];
        __syncthreads();

        if (epi) {
            const int dd = threadIdx.x >> 6;
            float z[4];
#pragma unroll
            for (int g = 0; g < 4; ++g) {
                const int r = (dd * 4 + g) * 4;
                z[g] = red[r][eb] + red[r + 1][eb] + red[r + 2][eb] + red[r + 3][eb]
                     + xzv[g];
            }
            float ig = 1.f / (1.f + __expf(-z[0]));
            float fg = 1.f / (1.f + __expf(-z[1]));
            float gg = tanhf(z[2]);
            float og = 1.f / (1.f + __expf(-z[3]));
            float c_new = fg * c_reg + ig * gg;
            float h_new = og * tanhf(c_new);
            bool msk = t < len_b;
            float h_out = msk ? h_new : hp_epi;
            c_reg = msk ? c_new : c_reg;
            hn[ed * 64 + eb] = h_out;
            hc_out[(size_t)tl * (D_ * 64) + ed * 64 + eb] = h_out;
        }

        if (tl != TC - 1)
            grid_barrier(bar, bar + 1);
    }
    if (epi) c_st[ed * 64 + eb] = c_reg;        // persist c for next chunk
}

// ---------------------------------------------------------------------------
// Transpose chunk h1c [tl][d][b] -> out [b][t0+tl][d]   (unchanged)
// ---------------------------------------------------------------------------
__global__ __launch_bounds__(256) void transpose_kernel(
    const float* __restrict__ h1c, float* __restrict__ out, int t0)
{
    const int tl   = blockIdx.x;
    const int dblk = blockIdx.y;
    __shared__ float tile[64][65];

    const int r  = threadIdx.x >> 2;
    const int cq = threadIdx.x & 3;

    const float* src = h1c + (size_t)tl * (D_ * 64) + (size_t)(dblk * 64 + r) * 64 + cq * 16;
#pragma unroll
    for (int j = 0; j < 4; ++j) {
        float4 v = *(const float4*)(src + j * 4);
        tile[r][cq * 16 + j * 4 + 0] = v.x;
        tile[r][cq * 16 + j * 4 + 1] = v.y;
        tile[r][cq * 16 + j * 4 + 2] = v.z;
        tile[r][cq * 16 + j * 4 + 3] = v.w;
    }
    __syncthreads();

    float* dst = out + (size_t)r * (U_ * D_) + (size_t)(t0 + tl) * D_ + dblk * 64 + cq * 16;
#pragma unroll
    for (int j = 0; j < 4; ++j) {
        float4 w;
        w.x = tile[cq * 16 + j * 4 + 0][r];
        w.y = tile[cq * 16 + j * 4 + 1][r];
        w.z = tile[cq * 16 + j * 4 + 2][r];
        w.w = tile[cq * 16 + j * 4 + 3][r];
        *(float4*)(dst + j * 4) = w;
    }
}

// ---------------------------------------------------------------------------
extern "C" void kernel_launch(void* const* d_in, const int* in_sizes, int n_in,
                              void* d_out, int out_size, void* d_ws, size_t ws_size,
                              hipStream_t stream)
{
    const int*   targets = (const int*)d_in[0];
    const int*   lens    = (const int*)d_in[1];
    const float* embed   = (const float*)d_in[2];
    const float* W0      = (const float*)d_in[3];
    const float* U0      = (const float*)d_in[4];
    const float* b0      = (const float*)d_in[5];
    const float* W1      = (const float*)d_in[6];
    const float* U1      = (const float*)d_in[7];
    const float* b1      = (const float*)d_in[8];
    float* out = (float*)d_out;
    float* ws  = (float*)d_ws;

    // workspace layout (floats)
    float* xz  = ws;                                   // TC*2560*64 = 10,485,760
    float* h0c = xz  + (size_t)TC * L4_ * 64;          // TC*640*64  =  2,621,440
    float* h1c = h0c + (size_t)TC * D_ * 64;           // TC*640*64
    float* st  = h1c + (size_t)TC * D_ * 64;           // 6 * 40,960 state buffers
    float* h0a = st;
    float* h0b = st + 40960;
    float* c0  = st + 2 * 40960;
    float* h1a = st + 3 * 40960;
    float* h1b = st + 4 * 40960;
    float* c1  = st + 5 * 40960;
    unsigned* bar = (unsigned*)(st + 6 * 40960);       // 64 floats reserved
    float* Up0 = st + 6 * 40960 + 64;                  // 640*2560 = 1,638,400
    float* Up1 = Up0 + (size_t)D_ * L4_;               // 640*2560
    // total ~19.25M floats ~= 77 MB

    // zero-init states + barrier words (ws is poisoned before every call)
    hipMemsetAsync(st, 0, (size_t)6 * 40960 * sizeof(float) + 256, stream);

    // one-time recurrent-weight transpose for both layers
    prep_up_kernel<<<dim3(D_, 2), dim3(256), 0, stream>>>(U0, U1, Up0, Up1);

    const dim3 gemm_grid(TC * 64 / 128, L4_ / 128);    // (32, 20)
    const dim3 blk(256);

    for (int ch = 0; ch < NCH; ++ch) {
        const int t0 = ch * TC;

        // layer 0 input transform: xz = embed[targets] @ W0 + b0
        gemm_kernel<0><<<gemm_grid, blk, 0, stream>>>(embed, targets, W0, b0, xz, E_, t0);

        // layer 0: 64 timesteps in one persistent launch
        lstm_seq_kernel<<<dim3(NBLK), blk, 0, stream>>>(
            xz, Up0, h0a, h0b, c0, lens, h0c, t0, bar);

        // layer 1 input transform: xz = h0c @ W1 + b1
        gemm_kernel<1><<<gemm_grid, blk, 0, stream>>>(h0c, targets, W1, b1, xz, D_, t0);

        // layer 1: 64 timesteps in one persistent launch
        lstm_seq_kernel<<<dim3(NBLK), blk, 0, stream>>>(
            xz, Up1, h1a, h1b, c1, lens, h1c, t0, bar);

        // emit chunk to output
        transpose_kernel<<<dim3(TC, 10), blk, 0, stream>>>(h1c, out, t0);
    }
}

// Round 3
// 29511.310 us; speedup vs baseline: 3.2891x; 3.2891x over previous
//
#include <hip/hip_runtime.h>
#include <math.h>

// Problem constants
#define B_   64
#define U_   1024
#define E_   512
#define D_   640
#define L4_  2560
#define TC   64          // time-chunk length
#define NCH  16          // number of chunks (TC*NCH == U_)
#define NBLK 160         // persistent blocks (4 d's each); 160 <= 256 CUs -> co-resident
#define SUBQ (NBLK / 8)  // blocks per sub-counter

// ---------------------------------------------------------------------------
// GEMM: C[t][n][b] = bias[n] + sum_k A[m][k] * W[k][n],  m = t*64 + b
// MODE 0: A row m comes from embed[targets[b][t0+t]] (gather), K = 512
// MODE 1: A is h0c with layout [t][k][b] (stride 640*64 per t),  K = 640
// Block tile 128x128, 256 threads, 8x8 per-thread tile, BK=8.  (unchanged)
// ---------------------------------------------------------------------------
template <int MODE>
__global__ __launch_bounds__(256) void gemm_kernel(
    const float* __restrict__ A,        // MODE0: embed [V][E]; MODE1: h0c [TC][640][64]
    const int*   __restrict__ targets,  // [B][U], used in MODE0
    const float* __restrict__ Wm,       // [K][2560]
    const float* __restrict__ bias,     // [2560]
    float* __restrict__ xz,             // [TC][2560][64]
    int K, int t0)
{
    const int tid = threadIdx.x;
    const int m0 = blockIdx.x * 128;
    const int n0 = blockIdx.y * 128;

    __shared__ float As[8][132];
    __shared__ float Bs[8][132];

    float acc[8][8];
#pragma unroll
    for (int i = 0; i < 8; ++i)
#pragma unroll
        for (int j = 0; j < 8; ++j) acc[i][j] = 0.f;

    const float* a_ptr;
    int a_ml = 0, a_kq = 0, a_k = 0;
    if (MODE == 0) {
        a_ml = tid & 127;
        a_kq = (tid >> 7) * 4;
        int m  = m0 + a_ml;
        int b  = m & 63;
        int tl = m >> 6;
        int idx = targets[b * U_ + t0 + tl];
        a_ptr = A + (size_t)idx * E_ + a_kq;
    } else {
        a_k  = tid >> 5;
        a_ml = (tid & 31) * 4;
        int m  = m0 + a_ml;
        int b  = m & 63;
        int tl = m >> 6;
        a_ptr = A + (size_t)tl * (D_ * 64) + (size_t)a_k * 64 + b;
    }
    const int b_k  = tid >> 5;
    const int b_n4 = (tid & 31) * 4;

    const int tx = tid & 15;
    const int ty = tid >> 4;

    for (int k0 = 0; k0 < K; k0 += 8) {
        if (MODE == 0) {
            float4 av = *(const float4*)(a_ptr + k0);
            As[a_kq + 0][a_ml] = av.x;
            As[a_kq + 1][a_ml] = av.y;
            As[a_kq + 2][a_ml] = av.z;
            As[a_kq + 3][a_ml] = av.w;
        } else {
            float4 av = *(const float4*)(a_ptr + (size_t)k0 * 64);
            *(float4*)&As[a_k][a_ml] = av;
        }
        {
            float4 bv = *(const float4*)(Wm + (size_t)(k0 + b_k) * L4_ + n0 + b_n4);
            *(float4*)&Bs[b_k][b_n4] = bv;
        }
        __syncthreads();

#pragma unroll
        for (int k = 0; k < 8; ++k) {
            float af[8], bf[8];
            *(float4*)&af[0] = *(const float4*)&As[k][ty * 8];
            *(float4*)&af[4] = *(const float4*)&As[k][ty * 8 + 4];
            *(float4*)&bf[0] = *(const float4*)&Bs[k][tx * 8];
            *(float4*)&bf[4] = *(const float4*)&Bs[k][tx * 8 + 4];
#pragma unroll
            for (int i = 0; i < 8; ++i)
#pragma unroll
                for (int j = 0; j < 8; ++j) acc[i][j] += af[i] * bf[j];
        }
        __syncthreads();
    }

#pragma unroll
    for (int i = 0; i < 8; ++i) {
        int m  = m0 + ty * 8 + i;
        int tl = m >> 6;
        int b  = m & 63;
        float* outp = xz + (size_t)tl * (L4_ * 64) + b;
#pragma unroll
        for (int j = 0; j < 8; ++j) {
            int n = n0 + tx * 8 + j;
            outp[(size_t)n * 64] = acc[i][j] + bias[n];
        }
    }
}

// ---------------------------------------------------------------------------
// Pre-transpose recurrent weights into per-block-group layout:
//   Upg[g][k][dd][gate] = Uw[k][gate*640 + (g*4+dd)],  g = d>>2, dd = d&3
// One block's slice (g fixed) is 640*16 floats = 40 KB, contiguous -> it is
// staged to LDS once per seq dispatch and read with broadcast ds_read_b128.
// ---------------------------------------------------------------------------
__global__ __launch_bounds__(256) void prep_up_kernel(
    const float* __restrict__ U0w, const float* __restrict__ U1w,
    float* __restrict__ Up0, float* __restrict__ Up1)
{
    const int k = blockIdx.x;                       // 0..639
    const float* Uw = blockIdx.y ? U1w : U0w;
    float*       Up = blockIdx.y ? Up1 : Up0;
    for (int d = threadIdx.x; d < D_; d += 256) {   // coalesced reads over d
        float4 v;
        v.x = Uw[(size_t)k * L4_ + d];
        v.y = Uw[(size_t)k * L4_ + 640  + d];
        v.z = Uw[(size_t)k * L4_ + 1280 + d];
        v.w = Uw[(size_t)k * L4_ + 1920 + d];
        *(float4*)(Up + ((((size_t)(d >> 2) * 640 + k) * 4) + (d & 3)) * 4) = v;
    }
}

// ---------------------------------------------------------------------------
// LLC-coherent scalar access helpers: relaxed agent-scope atomics compile to
// sc1-flagged global_load/store_dword -> bypass the non-coherent per-XCD L2,
// write-through/read-from LLC. This is what makes the barrier below legal
// WITHOUT any buffer_wbl2/buffer_inv cache maintenance (round-1's killer:
// per-block per-step RELEASE/ACQUIRE fences = 640 full-L2 wb/inv per step).
// ---------------------------------------------------------------------------
__device__ __forceinline__ float ldg_llc(const float* p) {
    return __hip_atomic_load(p, __ATOMIC_RELAXED, __HIP_MEMORY_SCOPE_AGENT);
}
__device__ __forceinline__ void stg_llc(float* p, float v) {
    __hip_atomic_store(p, v, __ATOMIC_RELAXED, __HIP_MEMORY_SCOPE_AGENT);
}

// ---------------------------------------------------------------------------
// Two-level, monotonic (no-reset) grid barrier. All counters relaxed.
//  - each wave's __syncthreads drains vmcnt -> this block's sc1 h-stores have
//    reached LLC before thread 0 bumps its sub-counter (RMW executes at LLC).
//  - sub-counter old==done*SUBQ-1 -> bump master; pollers spin on master.
//  - 'done' is an ABSOLUTE barrier index (host passes per-launch base), so
//    counters never reset -> no reset/arrival race, re-entrant across the 32
//    seq dispatches. No fences anywhere: h traffic is LLC-coherent by itself.
//  - sub-counters 128 B apart (one full TCC line each) so the 8 LLC RMW
//    streams never serialize on a shared line; master on its own line.
// Deadlock safety: NBLK=160 <= 256 CUs, 56 KB LDS, 256 thr -> every block
// resident on its own CU at dispatch; all blocks always co-resident.
// ---------------------------------------------------------------------------
__device__ __forceinline__ void grid_barrier(unsigned* bar, unsigned done)
{
    asm volatile("s_waitcnt vmcnt(0)" ::: "memory");
    __syncthreads();
    if (threadIdx.x == 0) {
        unsigned* sub    = bar + ((blockIdx.x & 7) << 5);   // 128B-separated lines
        unsigned* master = bar + (8 << 5);
        unsigned a = __hip_atomic_fetch_add(sub, 1u, __ATOMIC_RELAXED, __HIP_MEMORY_SCOPE_AGENT);
        if (a == done * SUBQ - 1u)
            __hip_atomic_fetch_add(master, 1u, __ATOMIC_RELAXED, __HIP_MEMORY_SCOPE_AGENT);
        const unsigned tgt = done * 8u;
        while (__hip_atomic_load(master, __ATOMIC_RELAXED, __HIP_MEMORY_SCOPE_AGENT) < tgt)
            __builtin_amdgcn_s_sleep(4);
    }
    __syncthreads();
}

// ---------------------------------------------------------------------------
// Persistent LSTM sequence kernel: TC=64 timesteps in ONE launch.
// Grid: 160 blocks x 256 threads; block owns hidden dims d0..d0+3.
// Thread (b, ks): b = tid&63, ks = tid>>6 (160 k's each). Up slice lives in
// LDS (staged once, broadcast ds_read_b128 per k -> conflict-free). h is read
// via sc1 LLC loads (16-deep double-buffered batches to hide ~500cy latency)
// and written via sc1 write-through stores. c-state in registers all chunk.
// ---------------------------------------------------------------------------
__global__ __launch_bounds__(256) void lstm_seq_kernel(
    const float* __restrict__ xz,      // [TC][2560][64]
    const float* __restrict__ Upg,     // [160][640][4][4] pre-transposed
    float* __restrict__ hA,            // [640][64] ping
    float* __restrict__ hB,            // [640][64] pong
    float* __restrict__ c_st,          // [640][64]
    const int* __restrict__ lens,      // [64]
    float* __restrict__ hc_out,        // [TC][640][64]
    int t0,
    unsigned* __restrict__ bar,
    unsigned bar_base)                 // absolute barrier index base for this launch
{
    const int tid = threadIdx.x;
    const int d0  = blockIdx.x * 4;
    const int b   = tid & 63;
    const int ks  = tid >> 6;            // 0..3
    const int kbeg = ks * 160;

    __shared__ float Upl[640 * 16];      // 40 KB: this block's Up slice
    __shared__ float red[64][64];        // 16 KB: [ (i=dd*4+gate)*4 + ks ][ b ]

    // stage Up slice to LDS (coalesced float4), once per dispatch
    {
        const float* upg = Upg + (size_t)blockIdx.x * (640 * 16);
#pragma unroll
        for (int i = 0; i < 10; ++i) {
            const int e = (i * 256 + tid) * 4;
            *(float4*)&Upl[e] = *(const float4*)(upg + e);
        }
    }

    // epilogue-private state: all 256 threads own one (d,b) cell
    const int ed = d0 + (tid >> 6);
    const int eb = tid & 63;
    float c_reg   = c_st[ed * 64 + eb];   // c never crosses blocks
    const int len_b = lens[eb];

    __syncthreads();                      // Upl ready

#define LOADB(HV, KK)                                                       \
    _Pragma("unroll")                                                       \
    for (int j = 0; j < 16; ++j)                                            \
        HV[j] = ldg_llc(hpb + (((KK) + j) << 6));

#define FMAB(HV, KK)                                                        \
    _Pragma("unroll")                                                       \
    for (int j = 0; j < 16; ++j) {                                          \
        const float hvv = HV[j];                                            \
        const int ko = ((KK) + j) << 4;                                     \
        const float4 u0 = *(const float4*)&Upl[ko];                         \
        const float4 u1 = *(const float4*)&Upl[ko + 4];                     \
        const float4 u2 = *(const float4*)&Upl[ko + 8];                     \
        const float4 u3 = *(const float4*)&Upl[ko + 12];                    \
        p[0]  += hvv * u0.x; p[1]  += hvv * u0.y;                           \
        p[2]  += hvv * u0.z; p[3]  += hvv * u0.w;                           \
        p[4]  += hvv * u1.x; p[5]  += hvv * u1.y;                           \
        p[6]  += hvv * u1.z; p[7]  += hvv * u1.w;                           \
        p[8]  += hvv * u2.x; p[9]  += hvv * u2.y;                           \
        p[10] += hvv * u2.z; p[11] += hvv * u2.w;                           \
        p[12] += hvv * u3.x; p[13] += hvv * u3.y;                           \
        p[14] += hvv * u3.z; p[15] += hvv * u3.w;                           \
    }

    for (int tl = 0; tl < TC; ++tl) {
        const int t = t0 + tl;
        const float* hp = (t & 1) ? hB : hA;    // same parity rule as before
        float*       hn = (t & 1) ? hA : hB;

        // prefetch epilogue operands early -> latency hidden under k-loop
        float xzv[4];
        {
            const float* xzp = xz + (size_t)tl * (L4_ * 64) + eb;
#pragma unroll
            for (int g = 0; g < 4; ++g)
                xzv[g] = xzp[(size_t)(ed + 640 * g) * 64];
        }
        const float hp_epi = ldg_llc(hp + ed * 64 + eb);

        float p[16];
#pragma unroll
        for (int i = 0; i < 16; ++i) p[i] = 0.f;

        const float* hpb = hp + b;
        float hvA[16], hvB[16];
        LOADB(hvA, kbeg)
        for (int i = 0; i < 5; ++i) {
            const int kk = kbeg + i * 32;
            LOADB(hvB, kk + 16)
            FMAB(hvA, kk)
            if (i < 4) { LOADB(hvA, kk + 32) }
            FMAB(hvB, kk + 16)
        }

#pragma unroll
        for (int i = 0; i < 16; ++i) red[(i << 2) | ks][b] = p[i];
        __syncthreads();

        {
            const int dd = tid >> 6;
            float z[4];
#pragma unroll
            for (int g = 0; g < 4; ++g) {
                const int r = ((dd * 4 + g) << 2);
                z[g] = red[r][eb] + red[r + 1][eb] + red[r + 2][eb] + red[r + 3][eb]
                     + xzv[g];
            }
            float ig = 1.f / (1.f + __expf(-z[0]));
            float fg = 1.f / (1.f + __expf(-z[1]));
            float gg = tanhf(z[2]);
            float og = 1.f / (1.f + __expf(-z[3]));
            float c_new = fg * c_reg + ig * gg;
            float h_new = og * tanhf(c_new);
            bool msk = t < len_b;
            float h_out = msk ? h_new : hp_epi;
            c_reg = msk ? c_new : c_reg;
            stg_llc(hn + ed * 64 + eb, h_out);                       // LLC write-through
            hc_out[(size_t)tl * (D_ * 64) + ed * 64 + eb] = h_out;   // plain (next kernel)
        }

        if (tl != TC - 1)
            grid_barrier(bar, bar_base + (unsigned)tl + 1u);
    }
    c_st[ed * 64 + eb] = c_reg;             // persist c for next chunk
#undef LOADB
#undef FMAB
}

// ---------------------------------------------------------------------------
// Transpose chunk h1c [tl][d][b] -> out [b][t0+tl][d]   (unchanged)
// ---------------------------------------------------------------------------
__global__ __launch_bounds__(256) void transpose_kernel(
    const float* __restrict__ h1c, float* __restrict__ out, int t0)
{
    const int tl   = blockIdx.x;
    const int dblk = blockIdx.y;
    __shared__ float tile[64][65];

    const int r  = threadIdx.x >> 2;
    const int cq = threadIdx.x & 3;

    const float* src = h1c + (size_t)tl * (D_ * 64) + (size_t)(dblk * 64 + r) * 64 + cq * 16;
#pragma unroll
    for (int j = 0; j < 4; ++j) {
        float4 v = *(const float4*)(src + j * 4);
        tile[r][cq * 16 + j * 4 + 0] = v.x;
        tile[r][cq * 16 + j * 4 + 1] = v.y;
        tile[r][cq * 16 + j * 4 + 2] = v.z;
        tile[r][cq * 16 + j * 4 + 3] = v.w;
    }
    __syncthreads();

    float* dst = out + (size_t)r * (U_ * D_) + (size_t)(t0 + tl) * D_ + dblk * 64 + cq * 16;
#pragma unroll
    for (int j = 0; j < 4; ++j) {
        float4 w;
        w.x = tile[cq * 16 + j * 4 + 0][r];
        w.y = tile[cq * 16 + j * 4 + 1][r];
        w.z = tile[cq * 16 + j * 4 + 2][r];
        w.w = tile[cq * 16 + j * 4 + 3][r];
        *(float4*)(dst + j * 4) = w;
    }
}

// ---------------------------------------------------------------------------
extern "C" void kernel_launch(void* const* d_in, const int* in_sizes, int n_in,
                              void* d_out, int out_size, void* d_ws, size_t ws_size,
                              hipStream_t stream)
{
    const int*   targets = (const int*)d_in[0];
    const int*   lens    = (const int*)d_in[1];
    const float* embed   = (const float*)d_in[2];
    const float* W0      = (const float*)d_in[3];
    const float* U0      = (const float*)d_in[4];
    const float* b0      = (const float*)d_in[5];
    const float* W1      = (const float*)d_in[6];
    const float* U1      = (const float*)d_in[7];
    const float* b1      = (const float*)d_in[8];
    float* out = (float*)d_out;
    float* ws  = (float*)d_ws;

    // workspace layout (floats)
    float* xz  = ws;                                   // TC*2560*64 = 10,485,760
    float* h0c = xz  + (size_t)TC * L4_ * 64;          // TC*640*64  =  2,621,440
    float* h1c = h0c + (size_t)TC * D_ * 64;           // TC*640*64
    float* st  = h1c + (size_t)TC * D_ * 64;           // 6 * 40,960 state buffers
    float* h0a = st;
    float* h0b = st + 40960;
    float* c0  = st + 2 * 40960;
    float* h1a = st + 3 * 40960;
    float* h1b = st + 4 * 40960;
    float* c1  = st + 5 * 40960;
    unsigned* bar = (unsigned*)(st + 6 * 40960);       // 512 uints (9 x 128B lines used)
    float* Up0 = st + 6 * 40960 + 512;                 // 640*2560 = 1,638,400
    float* Up1 = Up0 + (size_t)D_ * L4_;               // 640*2560
    // total ~19.25M floats ~= 77 MB (same as round-1 verified layout)

    // zero-init states + barrier words (ws is poisoned before every call)
    hipMemsetAsync(st, 0, (size_t)6 * 40960 * sizeof(float) + 2048, stream);

    // one-time recurrent-weight transpose for both layers
    prep_up_kernel<<<dim3(D_, 2), dim3(256), 0, stream>>>(U0, U1, Up0, Up1);

    const dim3 gemm_grid(TC * 64 / 128, L4_ / 128);    // (32, 20)
    const dim3 blk(256);

    unsigned launch_idx = 0;
    for (int ch = 0; ch < NCH; ++ch) {
        const int t0 = ch * TC;

        // layer 0 input transform: xz = embed[targets] @ W0 + b0
        gemm_kernel<0><<<gemm_grid, blk, 0, stream>>>(embed, targets, W0, b0, xz, E_, t0);

        // layer 0: 64 timesteps in one persistent launch
        lstm_seq_kernel<<<dim3(NBLK), blk, 0, stream>>>(
            xz, Up0, h0a, h0b, c0, lens, h0c, t0, bar, launch_idx * 63u);
        ++launch_idx;

        // layer 1 input transform: xz = h0c @ W1 + b1
        gemm_kernel<1><<<gemm_grid, blk, 0, stream>>>(h0c, targets, W1, b1, xz, D_, t0);

        // layer 1: 64 timesteps in one persistent launch
        lstm_seq_kernel<<<dim3(NBLK), blk, 0, stream>>>(
            xz, Up1, h1a, h1b, c1, lens, h1c, t0, bar, launch_idx * 63u);
        ++launch_idx;

        // emit chunk to output
        transpose_kernel<<<dim3(TC, 10), blk, 0, stream>>>(h1c, out, t0);
    }
}